// Round 1
// baseline (250.026 us; speedup 1.0000x reference)
//
#include <hip/hip_runtime.h>
#include <hip/hip_bf16.h>
#include <math.h>

#define ORDER  3
#define POINTS 16
#define NNODES 2048
#define D1 64
#define D2 32
#define POOL1 32
#define POOL2 8
#define LABELS 10

// -------------------------------------------------------------------------
// Kernel 1: feats[o,p,i] = mean_j cos(wm[o,p] * adj[o,i,j])
// One wave (64 lanes) per (i, o). Written as ms[i][o*16+p].
// cos via pre-scaled weight (1/2pi), v_fract, v_cos_f32.
// -------------------------------------------------------------------------
__global__ __launch_bounds__(64) void k_feats(const float* __restrict__ adj,
                                              const float* __restrict__ wm,
                                              float* __restrict__ ms) {
    const int i    = blockIdx.x;   // node row
    const int o    = blockIdx.y;   // order
    const int lane = threadIdx.x;  // 0..63

    const float INV2PI = 0.15915494309189535f;
    float wr[POINTS];
#pragma unroll
    for (int p = 0; p < POINTS; ++p)
        wr[p] = wm[o * POINTS + p] * INV2PI;

    const float4* row4 =
        reinterpret_cast<const float4*>(adj + ((size_t)o * NNODES + (size_t)i) * NNODES);

    float acc[POINTS];
#pragma unroll
    for (int p = 0; p < POINTS; ++p) acc[p] = 0.0f;

#pragma unroll
    for (int c = 0; c < NNODES / (4 * 64); ++c) {   // 8 chunks
        float4 a4 = row4[c * 64 + lane];
        float av[4] = {a4.x, a4.y, a4.z, a4.w};
#pragma unroll
        for (int e = 0; e < 4; ++e) {
            float a = av[e];
#pragma unroll
            for (int p = 0; p < POINTS; ++p) {
                float r = __builtin_amdgcn_fractf(a * wr[p]);  // [0,1) revolutions
                acc[p] += __builtin_amdgcn_cosf(r);            // cos(2*pi*r)
            }
        }
    }

    // wave reduce each accumulator (xor butterfly over 64 lanes)
#pragma unroll
    for (int p = 0; p < POINTS; ++p) {
        float v = acc[p];
#pragma unroll
        for (int off = 32; off >= 1; off >>= 1)
            v += __shfl_xor(v, off, 64);
        acc[p] = v;
    }

    if (lane == 0) {
        float* out = ms + (size_t)i * (ORDER * POINTS) + o * POINTS;
        const float rn = 1.0f / (float)NNODES;
#pragma unroll
        for (int p = 0; p < POINTS; ++p)
            out[p] = acc[p] * rn;
    }
}

// -------------------------------------------------------------------------
// Kernel 2: per-node-row MLP: 48 -> relu 64 -> relu 32 -> tanh 32 -> 8
// One thread per row; weights are wave-uniform loads (scalar path).
// Writes h2[2048][32] and s[2048][8].
// -------------------------------------------------------------------------
__global__ __launch_bounds__(64) void k_mlp(const float* __restrict__ ms,
                                            const float* __restrict__ w1,
                                            const float* __restrict__ b1,
                                            const float* __restrict__ w2,
                                            const float* __restrict__ b2,
                                            const float* __restrict__ p1,
                                            const float* __restrict__ pb1,
                                            const float* __restrict__ p2,
                                            const float* __restrict__ pb2,
                                            float* __restrict__ h2out,
                                            float* __restrict__ sout) {
    const int r = blockIdx.x * 64 + threadIdx.x;  // 0..2047

    const float4* mrow = reinterpret_cast<const float4*>(ms + (size_t)r * (ORDER * POINTS));

    // h1 = relu(ms @ w1 + b1)
    float h1[D1];
#pragma unroll
    for (int d = 0; d < D1; ++d) h1[d] = b1[d];
#pragma unroll
    for (int k4 = 0; k4 < (ORDER * POINTS) / 4; ++k4) {  // 12
        float4 mv = mrow[k4];
        float me[4] = {mv.x, mv.y, mv.z, mv.w};
#pragma unroll
        for (int e = 0; e < 4; ++e) {
            const float* wrow = w1 + (size_t)(k4 * 4 + e) * D1;
#pragma unroll
            for (int d = 0; d < D1; ++d)
                h1[d] = fmaf(me[e], wrow[d], h1[d]);
        }
    }
#pragma unroll
    for (int d = 0; d < D1; ++d) h1[d] = fmaxf(h1[d], 0.0f);

    // h2 = relu(h1 @ w2 + b2)
    float h2v[D2];
#pragma unroll
    for (int d = 0; d < D2; ++d) h2v[d] = b2[d];
#pragma unroll
    for (int k = 0; k < D1; ++k) {
        const float* wrow = w2 + (size_t)k * D2;
#pragma unroll
        for (int d = 0; d < D2; ++d)
            h2v[d] = fmaf(h1[k], wrow[d], h2v[d]);
    }
#pragma unroll
    for (int d = 0; d < D2; ++d) h2v[d] = fmaxf(h2v[d], 0.0f);

    // a = tanh(h2 @ p1 + pb1)
    float av[POOL1];
#pragma unroll
    for (int j = 0; j < POOL1; ++j) av[j] = pb1[j];
#pragma unroll
    for (int k = 0; k < D2; ++k) {
        const float* prow = p1 + (size_t)k * POOL1;
#pragma unroll
        for (int j = 0; j < POOL1; ++j)
            av[j] = fmaf(h2v[k], prow[j], av[j]);
    }
#pragma unroll
    for (int j = 0; j < POOL1; ++j) av[j] = tanhf(av[j]);

    // s = a @ p2 + pb2
    float sv[POOL2];
#pragma unroll
    for (int c = 0; c < POOL2; ++c) sv[c] = pb2[c];
#pragma unroll
    for (int j = 0; j < POOL1; ++j) {
        const float* prow = p2 + (size_t)j * POOL2;
#pragma unroll
        for (int c = 0; c < POOL2; ++c)
            sv[c] = fmaf(av[j], prow[c], sv[c]);
    }

    // stores (vectorized)
    float4* h2o = reinterpret_cast<float4*>(h2out + (size_t)r * D2);
#pragma unroll
    for (int q = 0; q < D2 / 4; ++q)
        h2o[q] = make_float4(h2v[q * 4 + 0], h2v[q * 4 + 1], h2v[q * 4 + 2], h2v[q * 4 + 3]);
    float4* so = reinterpret_cast<float4*>(sout + (size_t)r * POOL2);
#pragma unroll
    for (int q = 0; q < POOL2 / 4; ++q)
        so[q] = make_float4(sv[q * 4 + 0], sv[q * 4 + 1], sv[q * 4 + 2], sv[q * 4 + 3]);
}

// -------------------------------------------------------------------------
// Kernel 3: per-column softmax over nodes + pooled GEMM row.
// Block c (of 8): att[:,c] = softmax(s[:,c]); g[c,:] = att[:,c]^T @ h2
// -------------------------------------------------------------------------
__global__ __launch_bounds__(256) void k_pool(const float* __restrict__ sIn,
                                              const float* __restrict__ h2,
                                              float* __restrict__ g) {
    const int c = blockIdx.x;   // 0..7
    const int t = threadIdx.x;  // 0..255

    __shared__ float attc[NNODES];
    __shared__ float red[64];

    // pass 1: column max
    float pm = -1e30f;
    for (int r = t; r < NNODES; r += 256)
        pm = fmaxf(pm, sIn[(size_t)r * POOL2 + c]);
#pragma unroll
    for (int off = 32; off >= 1; off >>= 1)
        pm = fmaxf(pm, __shfl_xor(pm, off, 64));
    if ((t & 63) == 0) red[t >> 6] = pm;
    __syncthreads();
    const float mx = fmaxf(fmaxf(red[0], red[1]), fmaxf(red[2], red[3]));

    // pass 2: exp + sum (att column cached in LDS)
    float ps = 0.0f;
    for (int r = t; r < NNODES; r += 256) {
        float e = expf(sIn[(size_t)r * POOL2 + c] - mx);
        attc[r] = e;
        ps += e;
    }
#pragma unroll
    for (int off = 32; off >= 1; off >>= 1)
        ps += __shfl_xor(ps, off, 64);
    if ((t & 63) == 0) red[8 + (t >> 6)] = ps;
    __syncthreads();
    const float rinv = 1.0f / (red[8] + red[9] + red[10] + red[11]);

    // pass 3: g[c, d] = sum_r att[r] * h2[r, d]   (8 row-segments x 32 dims)
    const int d   = t & 31;
    const int seg = t >> 5;
    float acc = 0.0f;
    const float* h2p = h2 + (size_t)seg * 256 * D2 + d;
    const float* ap  = attc + seg * 256;
    for (int r = 0; r < 256; ++r)
        acc = fmaf(ap[r], h2p[(size_t)r * D2], acc);
    __syncthreads();           // done reading attc
    attc[t] = acc;             // reuse as reduction scratch
    __syncthreads();
    if (t < 32) {
        float v = 0.0f;
#pragma unroll
        for (int sg = 0; sg < 8; ++sg) v += attc[sg * 32 + t];
        g[c * D2 + t] = v * rinv;
    }
}

// -------------------------------------------------------------------------
// Kernel 4: logits = g @ cw + cb ; out = log_softmax(logits)
// 10 waves, one logit each; single-thread log-softmax over 10.
// -------------------------------------------------------------------------
__global__ __launch_bounds__(640) void k_logits(const float* __restrict__ g,
                                                const float* __restrict__ cw,
                                                const float* __restrict__ cb,
                                                float* __restrict__ out) {
    const int l    = threadIdx.x >> 6;  // 0..9
    const int lane = threadIdx.x & 63;
    __shared__ float lg[LABELS];

    float p = 0.0f;
    for (int k = lane; k < POOL2 * D2; k += 64)
        p = fmaf(g[k], cw[(size_t)k * LABELS + l], p);
#pragma unroll
    for (int off = 32; off >= 1; off >>= 1)
        p += __shfl_xor(p, off, 64);
    if (lane == 0) lg[l] = p + cb[l];
    __syncthreads();
    if (threadIdx.x == 0) {
        float m = lg[0];
#pragma unroll
        for (int i = 1; i < LABELS; ++i) m = fmaxf(m, lg[i]);
        float se = 0.0f;
#pragma unroll
        for (int i = 0; i < LABELS; ++i) se += expf(lg[i] - m);
        const float lse = m + logf(se);
#pragma unroll
        for (int i = 0; i < LABELS; ++i) out[i] = lg[i] - lse;
    }
}

extern "C" void kernel_launch(void* const* d_in, const int* in_sizes, int n_in,
                              void* d_out, int out_size, void* d_ws, size_t ws_size,
                              hipStream_t stream) {
    const float* adj = (const float*)d_in[0];
    const float* wm  = (const float*)d_in[1];
    const float* w1  = (const float*)d_in[2];
    const float* b1  = (const float*)d_in[3];
    const float* w2  = (const float*)d_in[4];
    const float* b2  = (const float*)d_in[5];
    const float* p1  = (const float*)d_in[6];
    const float* pb1 = (const float*)d_in[7];
    const float* p2  = (const float*)d_in[8];
    const float* pb2 = (const float*)d_in[9];
    const float* cw  = (const float*)d_in[10];
    const float* cb  = (const float*)d_in[11];
    float* out = (float*)d_out;

    float* ws = (float*)d_ws;
    float* ms  = ws;                           // 2048*48
    float* h2  = ms + (size_t)NNODES * ORDER * POINTS;  // 2048*32
    float* sS  = h2 + (size_t)NNODES * D2;              // 2048*8
    float* g   = sS + (size_t)NNODES * POOL2;           // 256

    hipLaunchKernelGGL(k_feats, dim3(NNODES, ORDER), dim3(64), 0, stream, adj, wm, ms);
    hipLaunchKernelGGL(k_mlp, dim3(NNODES / 64), dim3(64), 0, stream,
                       ms, w1, b1, w2, b2, p1, pb1, p2, pb2, h2, sS);
    hipLaunchKernelGGL(k_pool, dim3(POOL2), dim3(256), 0, stream, sS, h2, g);
    hipLaunchKernelGGL(k_logits, dim3(1), dim3(640), 0, stream, g, cw, cb, out);
}

// Round 2
// 148.044 us; speedup vs baseline: 1.6889x; 1.6889x over previous
//
#include <hip/hip_runtime.h>
#include <hip/hip_bf16.h>
#include <math.h>

#define ORDER  3
#define POINTS 16
#define NNODES 2048
#define D1 64
#define D2 32
#define POOL1 32
#define POOL2 8
#define LABELS 10

// -------------------------------------------------------------------------
// Kernel 1: feats[o,p,i] = mean_j cos(wm[o,p] * adj[o,i,j])
// One wave (64 lanes) per (i, o). Written as ms[i][o*16+p].
// cos via pre-scaled weight (1/2pi), v_fract, v_cos_f32.
// -------------------------------------------------------------------------
__global__ __launch_bounds__(64) void k_feats(const float* __restrict__ adj,
                                              const float* __restrict__ wm,
                                              float* __restrict__ ms) {
    const int i    = blockIdx.x;   // node row
    const int o    = blockIdx.y;   // order
    const int lane = threadIdx.x;  // 0..63

    const float INV2PI = 0.15915494309189535f;
    float wr[POINTS];
#pragma unroll
    for (int p = 0; p < POINTS; ++p)
        wr[p] = wm[o * POINTS + p] * INV2PI;

    const float4* row4 =
        reinterpret_cast<const float4*>(adj + ((size_t)o * NNODES + (size_t)i) * NNODES);

    float acc[POINTS];
#pragma unroll
    for (int p = 0; p < POINTS; ++p) acc[p] = 0.0f;

#pragma unroll
    for (int c = 0; c < NNODES / (4 * 64); ++c) {   // 8 chunks
        float4 a4 = row4[c * 64 + lane];
        float av[4] = {a4.x, a4.y, a4.z, a4.w};
#pragma unroll
        for (int e = 0; e < 4; ++e) {
            float a = av[e];
#pragma unroll
            for (int p = 0; p < POINTS; ++p) {
                float r = __builtin_amdgcn_fractf(a * wr[p]);  // [0,1) revolutions
                acc[p] += __builtin_amdgcn_cosf(r);            // cos(2*pi*r)
            }
        }
    }

    // wave reduce each accumulator (xor butterfly over 64 lanes)
#pragma unroll
    for (int p = 0; p < POINTS; ++p) {
        float v = acc[p];
#pragma unroll
        for (int off = 32; off >= 1; off >>= 1)
            v += __shfl_xor(v, off, 64);
        acc[p] = v;
    }

    if (lane == 0) {
        float* out = ms + (size_t)i * (ORDER * POINTS) + o * POINTS;
        const float rn = 1.0f / (float)NNODES;
#pragma unroll
        for (int p = 0; p < POINTS; ++p)
            out[p] = acc[p] * rn;
    }
}

// -------------------------------------------------------------------------
// Kernel 2 (rewritten): cooperative blocked MLP.
// 64 blocks x 256 threads; each block owns 32 rows. All weights and
// activations staged in LDS; each layer parallel over (out-dim, row-group).
// 48 -> relu 64 -> relu 32 -> tanh 32 -> 8
// -------------------------------------------------------------------------
__global__ __launch_bounds__(256) void k_mlp(const float* __restrict__ ms,
                                             const float* __restrict__ w1,
                                             const float* __restrict__ b1,
                                             const float* __restrict__ w2,
                                             const float* __restrict__ b2,
                                             const float* __restrict__ p1,
                                             const float* __restrict__ pb1,
                                             const float* __restrict__ p2,
                                             const float* __restrict__ pb2,
                                             float* __restrict__ h2out,
                                             float* __restrict__ sout) {
    const int t  = threadIdx.x;       // 0..255
    const int r0 = blockIdx.x * 32;   // first row of this block

    __shared__ float lms[32 * 48];    // input rows
    __shared__ float lw1[48 * D1];
    __shared__ float lh1[32 * D1];
    __shared__ float lw2[D1 * D2];
    __shared__ float lh2[32 * D2];
    __shared__ float lp1[D2 * POOL1];
    __shared__ float lav[32 * POOL1];
    __shared__ float lp2[POOL1 * POOL2];
    __shared__ float ls[32 * POOL2];
    __shared__ float lb1[D1], lb2[D2], lpb1[POOL1], lpb2[POOL2];

    // ---- stage everything into LDS (coalesced) ----
    for (int idx = t; idx < 32 * 48; idx += 256) lms[idx] = ms[(size_t)r0 * 48 + idx];
    for (int idx = t; idx < 48 * D1; idx += 256) lw1[idx] = w1[idx];
    for (int idx = t; idx < D1 * D2; idx += 256) lw2[idx] = w2[idx];
    for (int idx = t; idx < D2 * POOL1; idx += 256) lp1[idx] = p1[idx];
    if (t < POOL1 * POOL2) lp2[t] = p2[t];
    if (t < D1) lb1[t] = b1[t];
    if (t < D2) lb2[t] = b2[t];
    if (t < POOL1) lpb1[t] = pb1[t];
    if (t < POOL2) lpb2[t] = pb2[t];
    __syncthreads();

    // ---- layer 1: [32 x 48] @ [48 x 64] -> relu ----
    {
        const int dim = t & 63;       // output dim
        const int rg  = t >> 6;       // row group 0..3 (8 rows each)
        float acc[8];
#pragma unroll
        for (int j = 0; j < 8; ++j) acc[j] = 0.0f;
#pragma unroll
        for (int k4 = 0; k4 < 12; ++k4) {
            const float wa = lw1[(k4 * 4 + 0) * D1 + dim];
            const float wb = lw1[(k4 * 4 + 1) * D1 + dim];
            const float wc = lw1[(k4 * 4 + 2) * D1 + dim];
            const float wd = lw1[(k4 * 4 + 3) * D1 + dim];
#pragma unroll
            for (int j = 0; j < 8; ++j) {
                const float4 m4 = *reinterpret_cast<const float4*>(&lms[(rg * 8 + j) * 48 + k4 * 4]);
                acc[j] = fmaf(m4.x, wa, fmaf(m4.y, wb, fmaf(m4.z, wc, fmaf(m4.w, wd, acc[j]))));
            }
        }
        const float bb = lb1[dim];
#pragma unroll
        for (int j = 0; j < 8; ++j)
            lh1[(rg * 8 + j) * D1 + dim] = fmaxf(acc[j] + bb, 0.0f);
    }
    __syncthreads();

    // ---- layer 2: [32 x 64] @ [64 x 32] -> relu ----
    {
        const int dim = t & 31;
        const int rg  = t >> 5;       // 0..7 (4 rows each)
        float acc[4] = {0.0f, 0.0f, 0.0f, 0.0f};
#pragma unroll
        for (int k4 = 0; k4 < 16; ++k4) {
            const float wa = lw2[(k4 * 4 + 0) * D2 + dim];
            const float wb = lw2[(k4 * 4 + 1) * D2 + dim];
            const float wc = lw2[(k4 * 4 + 2) * D2 + dim];
            const float wd = lw2[(k4 * 4 + 3) * D2 + dim];
#pragma unroll
            for (int j = 0; j < 4; ++j) {
                const float4 h4 = *reinterpret_cast<const float4*>(&lh1[(rg * 4 + j) * D1 + k4 * 4]);
                acc[j] = fmaf(h4.x, wa, fmaf(h4.y, wb, fmaf(h4.z, wc, fmaf(h4.w, wd, acc[j]))));
            }
        }
        const float bb = lb2[dim];
#pragma unroll
        for (int j = 0; j < 4; ++j)
            lh2[(rg * 4 + j) * D2 + dim] = fmaxf(acc[j] + bb, 0.0f);
    }
    __syncthreads();

    // write h2 to global: 32 rows x 32 = 1024 floats = 256 float4, one/thread
    reinterpret_cast<float4*>(h2out)[(size_t)blockIdx.x * 256 + t] =
        reinterpret_cast<const float4*>(lh2)[t];

    // ---- layer 3: [32 x 32] @ [32 x 32] -> tanh ----
    {
        const int dim = t & 31;
        const int rg  = t >> 5;
        float acc[4] = {0.0f, 0.0f, 0.0f, 0.0f};
#pragma unroll
        for (int k4 = 0; k4 < 8; ++k4) {
            const float wa = lp1[(k4 * 4 + 0) * POOL1 + dim];
            const float wb = lp1[(k4 * 4 + 1) * POOL1 + dim];
            const float wc = lp1[(k4 * 4 + 2) * POOL1 + dim];
            const float wd = lp1[(k4 * 4 + 3) * POOL1 + dim];
#pragma unroll
            for (int j = 0; j < 4; ++j) {
                const float4 h4 = *reinterpret_cast<const float4*>(&lh2[(rg * 4 + j) * D2 + k4 * 4]);
                acc[j] = fmaf(h4.x, wa, fmaf(h4.y, wb, fmaf(h4.z, wc, fmaf(h4.w, wd, acc[j]))));
            }
        }
        const float bb = lpb1[dim];
#pragma unroll
        for (int j = 0; j < 4; ++j)
            lav[(rg * 4 + j) * POOL1 + dim] = tanhf(acc[j] + bb);
    }
    __syncthreads();

    // ---- layer 4: [32 x 32] @ [32 x 8], one output per thread ----
    {
        const int row = t >> 3;
        const int c   = t & 7;
        float acc = lpb2[c];
#pragma unroll
        for (int k = 0; k < POOL1; ++k)
            acc = fmaf(lav[row * POOL1 + k], lp2[k * POOL2 + c], acc);
        ls[row * POOL2 + c] = acc;
    }
    __syncthreads();

    // write s to global: 32 rows x 8 = 256 floats, one/thread, coalesced
    sout[(size_t)r0 * POOL2 + t] = ls[t];
}

// -------------------------------------------------------------------------
// Kernel 3: per-column softmax over nodes + pooled GEMM row.
// Block c (of 8): att[:,c] = softmax(s[:,c]); g[c,:] = att[:,c]^T @ h2
// -------------------------------------------------------------------------
__global__ __launch_bounds__(256) void k_pool(const float* __restrict__ sIn,
                                              const float* __restrict__ h2,
                                              float* __restrict__ g) {
    const int c = blockIdx.x;   // 0..7
    const int t = threadIdx.x;  // 0..255

    __shared__ float attc[NNODES];
    __shared__ float red[16];
    __shared__ float4 pp[32][8];

    // pass 1: column max
    float pm = -1e30f;
    for (int r = t; r < NNODES; r += 256)
        pm = fmaxf(pm, sIn[(size_t)r * POOL2 + c]);
#pragma unroll
    for (int off = 32; off >= 1; off >>= 1)
        pm = fmaxf(pm, __shfl_xor(pm, off, 64));
    if ((t & 63) == 0) red[t >> 6] = pm;
    __syncthreads();
    const float mx = fmaxf(fmaxf(red[0], red[1]), fmaxf(red[2], red[3]));

    // pass 2: exp + sum (att column cached in LDS)
    float ps = 0.0f;
    for (int r = t; r < NNODES; r += 256) {
        float e = expf(sIn[(size_t)r * POOL2 + c] - mx);
        attc[r] = e;
        ps += e;
    }
#pragma unroll
    for (int off = 32; off >= 1; off >>= 1)
        ps += __shfl_xor(ps, off, 64);
    if ((t & 63) == 0) red[8 + (t >> 6)] = ps;
    __syncthreads();
    const float rinv = 1.0f / (red[8] + red[9] + red[10] + red[11]);

    // pass 3: g[c, :] = sum_r att[r] * h2[r, :], float4 over dims
    const int d4  = t & 7;    // float4 column 0..7 (covers dims d4*4..+3)
    const int seg = t >> 3;   // 0..31, 64 rows each
    float4 acc = make_float4(0.f, 0.f, 0.f, 0.f);
    const float4* h2v = reinterpret_cast<const float4*>(h2);
    for (int j = 0; j < 64; ++j) {
        const int r = seg * 64 + ((j + seg * 8) & 63);  // bank-rotated attc access
        const float a = attc[r];
        const float4 h = h2v[(size_t)r * 8 + d4];
        acc.x = fmaf(a, h.x, acc.x);
        acc.y = fmaf(a, h.y, acc.y);
        acc.z = fmaf(a, h.z, acc.z);
        acc.w = fmaf(a, h.w, acc.w);
    }
    pp[seg][d4] = acc;
    __syncthreads();
    if (t < 8) {
        float4 s = make_float4(0.f, 0.f, 0.f, 0.f);
#pragma unroll
        for (int sg = 0; sg < 32; ++sg) {
            const float4 v = pp[sg][t];
            s.x += v.x; s.y += v.y; s.z += v.z; s.w += v.w;
        }
        s.x *= rinv; s.y *= rinv; s.z *= rinv; s.w *= rinv;
        reinterpret_cast<float4*>(g)[c * 8 + t] = s;
    }
}

// -------------------------------------------------------------------------
// Kernel 4: logits = g @ cw + cb ; out = log_softmax(logits)
// -------------------------------------------------------------------------
__global__ __launch_bounds__(640) void k_logits(const float* __restrict__ g,
                                                const float* __restrict__ cw,
                                                const float* __restrict__ cb,
                                                float* __restrict__ out) {
    const int l    = threadIdx.x >> 6;  // 0..9
    const int lane = threadIdx.x & 63;
    __shared__ float lg[LABELS];

    float p = 0.0f;
    for (int k = lane; k < POOL2 * D2; k += 64)
        p = fmaf(g[k], cw[(size_t)k * LABELS + l], p);
#pragma unroll
    for (int off = 32; off >= 1; off >>= 1)
        p += __shfl_xor(p, off, 64);
    if (lane == 0) lg[l] = p + cb[l];
    __syncthreads();
    if (threadIdx.x == 0) {
        float m = lg[0];
#pragma unroll
        for (int i = 1; i < LABELS; ++i) m = fmaxf(m, lg[i]);
        float se = 0.0f;
#pragma unroll
        for (int i = 0; i < LABELS; ++i) se += expf(lg[i] - m);
        const float lse = m + logf(se);
#pragma unroll
        for (int i = 0; i < LABELS; ++i) out[i] = lg[i] - lse;
    }
}

extern "C" void kernel_launch(void* const* d_in, const int* in_sizes, int n_in,
                              void* d_out, int out_size, void* d_ws, size_t ws_size,
                              hipStream_t stream) {
    const float* adj = (const float*)d_in[0];
    const float* wm  = (const float*)d_in[1];
    const float* w1  = (const float*)d_in[2];
    const float* b1  = (const float*)d_in[3];
    const float* w2  = (const float*)d_in[4];
    const float* b2  = (const float*)d_in[5];
    const float* p1  = (const float*)d_in[6];
    const float* pb1 = (const float*)d_in[7];
    const float* p2  = (const float*)d_in[8];
    const float* pb2 = (const float*)d_in[9];
    const float* cw  = (const float*)d_in[10];
    const float* cb  = (const float*)d_in[11];
    float* out = (float*)d_out;

    float* ws = (float*)d_ws;
    float* ms  = ws;                                    // 2048*48
    float* h2  = ms + (size_t)NNODES * ORDER * POINTS;  // 2048*32
    float* sS  = h2 + (size_t)NNODES * D2;              // 2048*8
    float* g   = sS + (size_t)NNODES * POOL2;           // 256

    hipLaunchKernelGGL(k_feats, dim3(NNODES, ORDER), dim3(64), 0, stream, adj, wm, ms);
    hipLaunchKernelGGL(k_mlp, dim3(NNODES / 32), dim3(256), 0, stream,
                       ms, w1, b1, w2, b2, p1, pb1, p2, pb2, h2, sS);
    hipLaunchKernelGGL(k_pool, dim3(POOL2), dim3(256), 0, stream, sS, h2, g);
    hipLaunchKernelGGL(k_logits, dim3(1), dim3(640), 0, stream, g, cw, cb, out);
}